// Round 1
// baseline (1161.081 us; speedup 1.0000x reference)
//
#include <hip/hip_runtime.h>
#include <hip/hip_bf16.h>
#include <stdint.h>

// Problem constants (match reference)
#define B_    16
#define NT_   64
#define T_    8
#define D_    25088
#define C_    1000
#define M_    (B_*NT_)      // 1024 rows
#define NPAD  1024          // C padded to 1024 for clean tiling
#define D4    (D_/4)        // 6272 float4 per row

#define BK_     32
#define KSPLIT  8
#define KCHUNK  (D_ / KSPLIT)     // 3136
#define KSTEPS  (KCHUNK / BK_)    // 98

typedef __attribute__((ext_vector_type(4))) unsigned short us4;
typedef __attribute__((ext_vector_type(8))) short bf16x8;
typedef __attribute__((ext_vector_type(4))) float f32x4;

__device__ __forceinline__ unsigned short f2bf(float f) {
    union { float f; unsigned u; } v; v.f = f;
    unsigned r = v.u + 0x7FFFu + ((v.u >> 16) & 1u);   // round-to-nearest-even
    return (unsigned short)(r >> 16);
}

// ---------------- Kernel 1: masked mean-pool, fp32 -> bf16 ----------------
__global__ __launch_bounds__(256) void pool_kernel(
    const float* __restrict__ feats, const int* __restrict__ lens,
    unsigned short* __restrict__ pooled)
{
    int d4 = blockIdx.x * 256 + threadIdx.x;
    if (d4 >= D4) return;
    int row = blockIdx.y;            // b*64 + n
    int b = row >> 6;
    int len = lens[b];               // 1..8, uniform per block (same b)
    float inv = 1.0f / (float)len;
    const float4* src = (const float4*)feats + (size_t)row * (T_ * D4) + d4;
    float ax = 0.f, ay = 0.f, az = 0.f, aw = 0.f;
    for (int t = 0; t < len; ++t) {
        float4 v = src[(size_t)t * D4];
        ax += v.x; ay += v.y; az += v.z; aw += v.w;
    }
    us4 o = { f2bf(ax*inv), f2bf(ay*inv), f2bf(az*inv), f2bf(aw*inv) };
    *(us4*)(pooled + (size_t)row * D_ + (size_t)d4 * 4) = o;
}

// ---------------- Kernel 2: W fp32 -> bf16, zero-pad rows C_..NPAD-1 ------
__global__ __launch_bounds__(256) void convw_kernel(
    const float* __restrict__ W, unsigned short* __restrict__ Wb)
{
    int d4 = blockIdx.x * 256 + threadIdx.x;
    if (d4 >= D4) return;
    int r = blockIdx.y;
    us4 o = {0, 0, 0, 0};
    if (r < C_) {
        float4 v = *((const float4*)W + (size_t)r * D4 + d4);
        o = (us4){ f2bf(v.x), f2bf(v.y), f2bf(v.z), f2bf(v.w) };
    }
    *(us4*)(Wb + (size_t)r * D_ + (size_t)d4 * 4) = o;
}

// ---------------- Kernel 3: bf16 MFMA GEMM with split-K -------------------
// A: pooled (M_ x D_) bf16, row-major (K contiguous)
// B: Wb (NPAD x D_) bf16, row-major (K contiguous) == B^T layout
// C: logits (M_ x NPAD) fp32, accumulated via atomicAdd across KSPLIT
__device__ __forceinline__ void async16(const void* g, void* l) {
    __builtin_amdgcn_global_load_lds(
        (const __attribute__((address_space(1))) void*)g,
        (__attribute__((address_space(3))) void*)l, 16, 0, 0);
}

__global__ __launch_bounds__(256) void gemm_kernel(
    const unsigned short* __restrict__ A, const unsigned short* __restrict__ Bm,
    float* __restrict__ Cout)
{
    __shared__ unsigned short lA[128 * BK_];   // 8 KB, [row][k] k-contiguous
    __shared__ unsigned short lB[128 * BK_];   // 8 KB

    const int t    = threadIdx.x;
    const int w    = t >> 6;
    const int lane = t & 63;
    const int wm   = w >> 1, wn = w & 1;       // 2x2 waves, 64x64 each
    const int quad = lane >> 4, l16 = lane & 15;

    const int m0 = blockIdx.y * 128;
    const int n0 = blockIdx.x * 128;
    const int k0 = blockIdx.z * KCHUNK;

    // staging: chunk c = t (round 0) / 256+t (round 1); 16 B per lane
    const int srow = t >> 2;                   // 0..63
    const int skk  = (t & 3) * 8;
    const unsigned short* gA0 = A  + (size_t)(m0 + srow) * D_ + k0 + skk;
    const unsigned short* gA1 = gA0 + (size_t)64 * D_;
    const unsigned short* gB0 = Bm + (size_t)(n0 + srow) * D_ + k0 + skk;
    const unsigned short* gB1 = gB0 + (size_t)64 * D_;
    unsigned short* lA0 = &lA[w * 512];        // wave-uniform LDS bases
    unsigned short* lA1 = &lA[2048 + w * 512];
    unsigned short* lB0 = &lB[w * 512];
    unsigned short* lB1 = &lB[2048 + w * 512];

    f32x4 acc[4][4];
#pragma unroll
    for (int mi = 0; mi < 4; ++mi)
#pragma unroll
        for (int ni = 0; ni < 4; ++ni)
            acc[mi][ni] = (f32x4){0.f, 0.f, 0.f, 0.f};

    for (int ks = 0; ks < KSTEPS; ++ks) {
        async16(gA0, lA0); async16(gA1, lA1);
        async16(gB0, lB0); async16(gB1, lB1);
        gA0 += BK_; gA1 += BK_; gB0 += BK_; gB1 += BK_;
        __syncthreads();   // compiler drains vmcnt before s_barrier

        bf16x8 af[4], bfr[4];
#pragma unroll
        for (int mi = 0; mi < 4; ++mi)
            af[mi] = *(const bf16x8*)&lA[(wm*64 + mi*16 + l16) * BK_ + quad*8];
#pragma unroll
        for (int ni = 0; ni < 4; ++ni)
            bfr[ni] = *(const bf16x8*)&lB[(wn*64 + ni*16 + l16) * BK_ + quad*8];
#pragma unroll
        for (int mi = 0; mi < 4; ++mi)
#pragma unroll
            for (int ni = 0; ni < 4; ++ni)
                acc[mi][ni] = __builtin_amdgcn_mfma_f32_16x16x32_bf16(
                    af[mi], bfr[ni], acc[mi][ni], 0, 0, 0);
        __syncthreads();
    }

    // epilogue: C/D layout col=lane&15, row=quad*4+reg
#pragma unroll
    for (int mi = 0; mi < 4; ++mi) {
        int rbase = m0 + wm*64 + mi*16 + quad*4;
#pragma unroll
        for (int ni = 0; ni < 4; ++ni) {
            int col = n0 + wn*64 + ni*16 + l16;
#pragma unroll
            for (int rg = 0; rg < 4; ++rg)
                atomicAdd(&Cout[(size_t)(rbase + rg) * NPAD + col], acc[mi][ni][rg]);
        }
    }
}

// ---------------- Kernel 4: per-row logsumexp + NLL accumulation ----------
__global__ __launch_bounds__(256) void nll_kernel(
    const float* __restrict__ logits, const float* __restrict__ bias,
    const int* __restrict__ labels, const int* __restrict__ ntp,
    float* __restrict__ accum)   // accum[0]=sum(float), accum[1]=count(int)
{
    int row = blockIdx.x;
    int n = row & (NT_ - 1);
    int nt = *ntp;
    int lbl = labels[row];
    if (n >= nt || lbl < 0) return;   // uniform across block

    const float* lg = logits + (size_t)row * NPAD;
    int t = threadIdx.x;
    __shared__ float red[4], red2[4];

    float lmax = -1e30f;
    for (int c = t; c < C_; c += 256) lmax = fmaxf(lmax, lg[c] + bias[c]);
#pragma unroll
    for (int off = 32; off > 0; off >>= 1) lmax = fmaxf(lmax, __shfl_down(lmax, off, 64));
    if ((t & 63) == 0) red[t >> 6] = lmax;
    __syncthreads();
    float gmax = fmaxf(fmaxf(red[0], red[1]), fmaxf(red[2], red[3]));

    float lsum = 0.f;
    for (int c = t; c < C_; c += 256) lsum += expf(lg[c] + bias[c] - gmax);
#pragma unroll
    for (int off = 32; off > 0; off >>= 1) lsum += __shfl_down(lsum, off, 64);
    if ((t & 63) == 0) red2[t >> 6] = lsum;
    __syncthreads();

    if (t == 0) {
        float s = red2[0] + red2[1] + red2[2] + red2[3];
        float target = lg[lbl] + bias[lbl];
        float nll = logf(s) + gmax - target;
        atomicAdd(&accum[0], nll);
        atomicAdd((int*)accum + 1, 1);
    }
}

// ---------------- Kernel 5: finalize scalar -------------------------------
__global__ void fin_kernel(const float* __restrict__ accum, float* __restrict__ out) {
    int cnt = ((const int*)accum)[1];
    out[0] = accum[0] / (float)(cnt > 0 ? cnt : 1);
}

extern "C" void kernel_launch(void* const* d_in, const int* in_sizes, int n_in,
                              void* d_out, int out_size, void* d_ws, size_t ws_size,
                              hipStream_t stream)
{
    const float* feats = (const float*)d_in[0];
    const float* W     = (const float*)d_in[1];
    const float* bias  = (const float*)d_in[2];
    const int*   ntp   = (const int*)d_in[3];
    const int*   labels= (const int*)d_in[4];
    const int*   lens  = (const int*)d_in[5];
    float* out = (float*)d_out;

    // ws layout
    const size_t POOLED_BYTES = (size_t)M_   * D_ * 2;   // 51,380,224
    const size_t WB_BYTES     = (size_t)NPAD * D_ * 2;   // 51,380,224
    const size_t LOGIT_BYTES  = (size_t)M_ * NPAD * 4;   // 4,194,304
    uint8_t* ws = (uint8_t*)d_ws;
    unsigned short* pooled = (unsigned short*)ws;
    unsigned short* Wb     = (unsigned short*)(ws + POOLED_BYTES);
    float* logits          = (float*)(ws + POOLED_BYTES + WB_BYTES);
    float* accum           = (float*)(ws + POOLED_BYTES + WB_BYTES + LOGIT_BYTES);

    // zero logits + accumulators (re-poisoned to 0xAA before every call)
    hipMemsetAsync(logits, 0, LOGIT_BYTES + 256, stream);

    dim3 gpool((D4 + 255) / 256, M_);
    pool_kernel<<<gpool, 256, 0, stream>>>(feats, lens, pooled);

    dim3 gconv((D4 + 255) / 256, NPAD);
    convw_kernel<<<gconv, 256, 0, stream>>>(W, Wb);

    dim3 ggemm(NPAD / 128, M_ / 128, KSPLIT);   // (8, 8, 8)
    gemm_kernel<<<ggemm, 256, 0, stream>>>(pooled, Wb, logits);

    nll_kernel<<<dim3(M_), 256, 0, stream>>>(logits, bias, labels, ntp, accum);

    fin_kernel<<<1, 1, 0, stream>>>(accum, out);
}

// Round 3
// 1147.924 us; speedup vs baseline: 1.0115x; 1.0115x over previous
//
#include <hip/hip_runtime.h>
#include <hip/hip_bf16.h>
#include <stdint.h>

// Problem constants (match reference)
#define B_    16
#define NT_   64
#define T_    8
#define D_    25088
#define C_    1000
#define M_    (B_*NT_)      // 1024 rows
#define NPAD  1024          // C padded to 1024 for clean tiling
#define D4    (D_/4)        // 6272 float4 per row

#define BK_     32
#define KSPLIT  8
#define KCHUNK  (D_ / KSPLIT)     // 3136
#define KSTEPS  (KCHUNK / BK_)    // 98

typedef __attribute__((ext_vector_type(4))) unsigned short us4;
typedef __attribute__((ext_vector_type(8))) short bf16x8;
typedef __attribute__((ext_vector_type(4))) float f32x4;

__device__ __forceinline__ unsigned short f2bf(float f) {
    union { float f; unsigned u; } v; v.f = f;
    unsigned r = v.u + 0x7FFFu + ((v.u >> 16) & 1u);   // round-to-nearest-even
    return (unsigned short)(r >> 16);
}

// ---------------- Kernel 1: masked mean-pool, fp32 -> bf16 ----------------
__global__ __launch_bounds__(256) void pool_kernel(
    const float* __restrict__ feats, const int* __restrict__ lens,
    unsigned short* __restrict__ pooled)
{
    int d4 = blockIdx.x * 256 + threadIdx.x;
    if (d4 >= D4) return;
    int row = blockIdx.y;            // b*64 + n
    int b = row >> 6;
    int len = lens[b];               // 1..8, uniform per block (same b)
    float inv = 1.0f / (float)len;
    const float4* src = (const float4*)feats + (size_t)row * (T_ * D4) + d4;
    float ax = 0.f, ay = 0.f, az = 0.f, aw = 0.f;
    for (int t = 0; t < len; ++t) {
        float4 v = src[(size_t)t * D4];
        ax += v.x; ay += v.y; az += v.z; aw += v.w;
    }
    us4 o = { f2bf(ax*inv), f2bf(ay*inv), f2bf(az*inv), f2bf(aw*inv) };
    *(us4*)(pooled + (size_t)row * D_ + (size_t)d4 * 4) = o;
}

// ---------------- Kernel 2: W fp32 -> bf16, zero-pad rows C_..NPAD-1 ------
__global__ __launch_bounds__(256) void convw_kernel(
    const float* __restrict__ W, unsigned short* __restrict__ Wb)
{
    int d4 = blockIdx.x * 256 + threadIdx.x;
    if (d4 >= D4) return;
    int r = blockIdx.y;
    us4 o = {0, 0, 0, 0};
    if (r < C_) {
        float4 v = *((const float4*)W + (size_t)r * D4 + d4);
        o = (us4){ f2bf(v.x), f2bf(v.y), f2bf(v.z), f2bf(v.w) };
    }
    *(us4*)(Wb + (size_t)r * D_ + (size_t)d4 * 4) = o;
}

// ---------------- Kernel 3: bf16 MFMA GEMM with split-K -------------------
// A: pooled (M_ x D_) bf16, row-major (K contiguous)
// B: Wb (NPAD x D_) bf16, row-major (K contiguous) == B^T layout
// Out: partials[z] (M_ x NPAD) fp32 — plain stores, no atomics.
__device__ __forceinline__ void async16(const void* g, void* l) {
    __builtin_amdgcn_global_load_lds(
        (const __attribute__((address_space(1))) void*)g,
        (__attribute__((address_space(3))) void*)l, 16, 0, 0);
}

__global__ __launch_bounds__(256) void gemm_kernel(
    const unsigned short* __restrict__ A, const unsigned short* __restrict__ Bm,
    float* __restrict__ partials)
{
    __shared__ unsigned short lA[128 * BK_];   // 8 KB, [row][k] k-contiguous
    __shared__ unsigned short lB[128 * BK_];   // 8 KB

    const int t    = threadIdx.x;
    const int w    = t >> 6;
    const int lane = t & 63;
    const int wm   = w >> 1, wn = w & 1;       // 2x2 waves, 64x64 each
    const int quad = lane >> 4, l16 = lane & 15;

    const int m0 = blockIdx.y * 128;
    const int n0 = blockIdx.x * 128;
    const int k0 = blockIdx.z * KCHUNK;

    // staging: 16 B per lane; LDS dest = wave-uniform base + lane*16
    const int srow = t >> 2;                   // 0..63
    const int skk  = (t & 3) * 8;
    const unsigned short* gA0 = A  + (size_t)(m0 + srow) * D_ + k0 + skk;
    const unsigned short* gA1 = gA0 + (size_t)64 * D_;
    const unsigned short* gB0 = Bm + (size_t)(n0 + srow) * D_ + k0 + skk;
    const unsigned short* gB1 = gB0 + (size_t)64 * D_;
    unsigned short* lA0 = &lA[w * 512];        // wave-uniform LDS bases
    unsigned short* lA1 = &lA[2048 + w * 512];
    unsigned short* lB0 = &lB[w * 512];
    unsigned short* lB1 = &lB[2048 + w * 512];

    f32x4 acc[4][4];
#pragma unroll
    for (int mi = 0; mi < 4; ++mi)
#pragma unroll
        for (int ni = 0; ni < 4; ++ni)
            acc[mi][ni] = (f32x4){0.f, 0.f, 0.f, 0.f};

    for (int ks = 0; ks < KSTEPS; ++ks) {
        async16(gA0, lA0); async16(gA1, lA1);
        async16(gB0, lB0); async16(gB1, lB1);
        gA0 += BK_; gA1 += BK_; gB0 += BK_; gB1 += BK_;
        __syncthreads();   // compiler drains vmcnt before s_barrier

        bf16x8 af[4], bfr[4];
#pragma unroll
        for (int mi = 0; mi < 4; ++mi)
            af[mi] = *(const bf16x8*)&lA[(wm*64 + mi*16 + l16) * BK_ + quad*8];
#pragma unroll
        for (int ni = 0; ni < 4; ++ni)
            bfr[ni] = *(const bf16x8*)&lB[(wn*64 + ni*16 + l16) * BK_ + quad*8];
#pragma unroll
        for (int mi = 0; mi < 4; ++mi)
#pragma unroll
            for (int ni = 0; ni < 4; ++ni)
                acc[mi][ni] = __builtin_amdgcn_mfma_f32_16x16x32_bf16(
                    af[mi], bfr[ni], acc[mi][ni], 0, 0, 0);
        __syncthreads();
    }

    // epilogue: plain stores to this z-slice's partial buffer
    // C/D layout col=lane&15, row=quad*4+reg
    float* P = partials + (size_t)blockIdx.z * M_ * NPAD;
#pragma unroll
    for (int mi = 0; mi < 4; ++mi) {
        int rbase = m0 + wm*64 + mi*16 + quad*4;
#pragma unroll
        for (int ni = 0; ni < 4; ++ni) {
            int col = n0 + wn*64 + ni*16 + l16;
#pragma unroll
            for (int rg = 0; rg < 4; ++rg)
                P[(size_t)(rbase + rg) * NPAD + col] = acc[mi][ni][rg];
        }
    }
}

// ---------------- Kernel 4: reduce partials + logsumexp + NLL -------------
__global__ __launch_bounds__(256) void nll_kernel(
    const float* __restrict__ partials, const float* __restrict__ bias,
    const int* __restrict__ labels, const int* __restrict__ ntp,
    float* __restrict__ accum)   // accum[0]=sum(float), accum[1]=count(int)
{
    int row = blockIdx.x;
    int n = row & (NT_ - 1);
    int nt = *ntp;
    int lbl = labels[row];
    if (n >= nt || lbl < 0) return;   // uniform across block

    int t = threadIdx.x;
    __shared__ float red[4], red2[4];

    // each active thread owns 4 consecutive cols: C_=1000 = 250*4
    float v0 = -1e30f, v1 = -1e30f, v2 = -1e30f, v3 = -1e30f;
    if (t < 250) {
        size_t off = (size_t)row * NPAD + t * 4;
        float4 s = *(const float4*)(bias + t * 4);
        v0 = s.x; v1 = s.y; v2 = s.z; v3 = s.w;
#pragma unroll
        for (int z = 0; z < KSPLIT; ++z) {
            float4 p = *(const float4*)(partials + (size_t)z * M_ * NPAD + off);
            v0 += p.x; v1 += p.y; v2 += p.z; v3 += p.w;
        }
    }

    float lmax = fmaxf(fmaxf(v0, v1), fmaxf(v2, v3));
#pragma unroll
    for (int off = 32; off > 0; off >>= 1) lmax = fmaxf(lmax, __shfl_down(lmax, off, 64));
    if ((t & 63) == 0) red[t >> 6] = lmax;
    __syncthreads();
    float gmax = fmaxf(fmaxf(red[0], red[1]), fmaxf(red[2], red[3]));

    float lsum = 0.f;
    if (t < 250)
        lsum = expf(v0 - gmax) + expf(v1 - gmax) + expf(v2 - gmax) + expf(v3 - gmax);
#pragma unroll
    for (int off = 32; off > 0; off >>= 1) lsum += __shfl_down(lsum, off, 64);
    if ((t & 63) == 0) red2[t >> 6] = lsum;
    __syncthreads();

    if (t == 0) {
        float s = red2[0] + red2[1] + red2[2] + red2[3];
        float target = bias[lbl];
        size_t toff = (size_t)row * NPAD + lbl;
#pragma unroll
        for (int z = 0; z < KSPLIT; ++z)
            target += partials[(size_t)z * M_ * NPAD + toff];
        float nll = logf(s) + gmax - target;
        atomicAdd(&accum[0], nll);
        atomicAdd((int*)accum + 1, 1);
    }
}

// ---------------- Kernel 5: finalize scalar -------------------------------
__global__ void fin_kernel(const float* __restrict__ accum, float* __restrict__ out) {
    int cnt = ((const int*)accum)[1];
    out[0] = accum[0] / (float)(cnt > 0 ? cnt : 1);
}

extern "C" void kernel_launch(void* const* d_in, const int* in_sizes, int n_in,
                              void* d_out, int out_size, void* d_ws, size_t ws_size,
                              hipStream_t stream)
{
    const float* feats = (const float*)d_in[0];
    const float* W     = (const float*)d_in[1];
    const float* bias  = (const float*)d_in[2];
    const int*   ntp   = (const int*)d_in[3];
    const int*   labels= (const int*)d_in[4];
    const int*   lens  = (const int*)d_in[5];
    float* out = (float*)d_out;

    // ws layout
    const size_t POOLED_BYTES = (size_t)M_   * D_ * 2;            // 51,380,224
    const size_t WB_BYTES     = (size_t)NPAD * D_ * 2;            // 51,380,224
    const size_t PART_BYTES   = (size_t)KSPLIT * M_ * NPAD * 4;   // 33,554,432
    uint8_t* ws = (uint8_t*)d_ws;
    unsigned short* pooled = (unsigned short*)ws;
    unsigned short* Wb     = (unsigned short*)(ws + POOLED_BYTES);
    float* partials        = (float*)(ws + POOLED_BYTES + WB_BYTES);
    float* accum           = (float*)(ws + POOLED_BYTES + WB_BYTES + PART_BYTES);

    // zero only the nll accumulators (ws is poisoned 0xAA before every call)
    hipMemsetAsync(accum, 0, 16, stream);

    dim3 gpool((D4 + 255) / 256, M_);
    pool_kernel<<<gpool, 256, 0, stream>>>(feats, lens, pooled);

    dim3 gconv((D4 + 255) / 256, NPAD);
    convw_kernel<<<gconv, 256, 0, stream>>>(W, Wb);

    dim3 ggemm(NPAD / 128, M_ / 128, KSPLIT);   // (8, 8, 8)
    gemm_kernel<<<ggemm, 256, 0, stream>>>(pooled, Wb, partials);

    nll_kernel<<<dim3(M_), 256, 0, stream>>>(partials, bias, labels, ntp, accum);

    fin_kernel<<<1, 1, 0, stream>>>(accum, out);
}